// Round 1
// baseline (452.710 us; speedup 1.0000x reference)
//
#include <hip/hip_runtime.h>
#include <cstddef>
#include <math.h>

// Problem constants (match reference)
#define S_TOK 4096
#define MDIM  2048
#define NE    32
#define CAP   256     // ceil(4096/32 * 1.0 * 2) = 256
#define TPB   256
#define TOKB  4       // tokens per block in gating kernel

// Workspace layout. Fields before `e1a` must be zeroed each launch.
struct Ws {
    int   counts[NE];        // pre-capacity per-expert token counts
    int   ecount[NE];        // per-expert assigned-list length (== counts)
    int   loc_s[S_TOK];      // sum of kept locations per token
    int   keptA[S_TOK];      // top-1 expert kept?
    int   keptB[S_TOK];      // top-2 expert kept?
    float gate_sum[NE];      // sum of softmax gates per expert (for me)
    // --- uninitialized below (always written before read) ---
    int   e1a[S_TOK];
    int   e2a[S_TOK];
    float g1a[S_TOK];
    float g2a[S_TOK];
    int   etok[NE * S_TOK];  // per-expert assigned token ids
    float eval[NE * S_TOK];  // per-expert assigned raw logits
};

// Kernel 1: logits (fp64 accumulate), softmax, top-2, push to expert lists.
// One block handles TOKB tokens. Thread (e=tid&31, seg=tid>>5) computes a
// 256-wide segment of the dot product for expert e for all TOKB tokens.
__global__ __launch_bounds__(TPB) void k_gate(const float* __restrict__ x,
                                              const float* __restrict__ wg,
                                              Ws* __restrict__ ws) {
    __shared__ float4 xs4[TOKB * 512];           // 32 KB: x tile
    __shared__ double part[8][NE][TOKB];         // 8 KB: partial dots
    __shared__ float  logitsF[TOKB][NE];         // fp32 logits (match np values)
    __shared__ float  gsumL[NE];

    const int tid = threadIdx.x;
    const int t0  = blockIdx.x * TOKB;

    if (tid < NE) gsumL[tid] = 0.f;

    // stage x tile (coalesced float4)
    const float4* x4 = (const float4*)x;
    #pragma unroll
    for (int k = 0; k < (TOKB * 512) / TPB; ++k) {
        int idx = tid + k * TPB;
        xs4[idx] = x4[(size_t)t0 * 512 + idx];
    }
    __syncthreads();

    const int e   = tid & 31;
    const int seg = tid >> 5;   // 0..7
    double acc[TOKB];
    #pragma unroll
    for (int i = 0; i < TOKB; ++i) acc[i] = 0.0;

    const float4* wg4 = (const float4*)wg;       // wg row = 512 float4
    for (int j4 = 0; j4 < 64; ++j4) {
        float4 w = wg4[e * 512 + seg * 64 + j4];
        #pragma unroll
        for (int tt = 0; tt < TOKB; ++tt) {
            float4 xv = xs4[tt * 512 + seg * 64 + j4];   // LDS broadcast
            acc[tt] += (double)xv.x * w.x + (double)xv.y * w.y +
                       (double)xv.z * w.z + (double)xv.w * w.w;
        }
    }
    #pragma unroll
    for (int tt = 0; tt < TOKB; ++tt) part[seg][e][tt] = acc[tt];
    __syncthreads();

    if (tid < TOKB * 32) {
        int tok = tid >> 5;
        int ee  = tid & 31;
        double s = 0.0;
        #pragma unroll
        for (int sg = 0; sg < 8; ++sg) s += part[sg][ee][tok];
        logitsF[tok][ee] = (float)s;
    }
    __syncthreads();

    // Per-token top-2 + softmax. Each 32-lane half-wave handles one token.
    const int lane = tid & 63;
    const int half = lane >> 5;                  // 0/1
    const int grp  = (tid >> 6) * 2 + half;      // local token id
    const int le   = lane & 31;

    if (grp < TOKB) {
        float l = logitsF[grp][le];

        // top-1 (ties -> lower index, matching jax.lax.top_k)
        float v1 = l; int e1 = le;
        #pragma unroll
        for (int m = 16; m >= 1; m >>= 1) {
            float ov = __shfl_xor(v1, m);
            int   oi = __shfl_xor(e1, m);
            if (ov > v1 || (ov == v1 && oi < e1)) { v1 = ov; e1 = oi; }
        }
        // top-2
        float v2 = (le == e1) ? -INFINITY : l;
        int   e2 = (le == e1) ? 0x7fffffff : le;
        #pragma unroll
        for (int m = 16; m >= 1; m >>= 1) {
            float ov = __shfl_xor(v2, m);
            int   oi = __shfl_xor(e2, m);
            if (ov > v2 || (ov == v2 && oi < e2)) { v2 = ov; e2 = oi; }
        }
        // softmax
        float p = expf(l - v1);
        float ssum = p;
        #pragma unroll
        for (int m = 16; m >= 1; m >>= 1) ssum += __shfl_xor(ssum, m);
        float gate = p / ssum;
        atomicAdd(&gsumL[le], gate);

        float g1 = __shfl(gate, (half << 5) + e1);
        float g2 = __shfl(gate, (half << 5) + e2);

        if (le == 0) {
            int t = t0 + grp;
            atomicAdd(&ws->counts[e1], 1);
            atomicAdd(&ws->counts[e2], 1);
            int i1 = atomicAdd(&ws->ecount[e1], 1);
            ws->etok[e1 * S_TOK + i1] = t;
            ws->eval[e1 * S_TOK + i1] = v1;
            int i2 = atomicAdd(&ws->ecount[e2], 1);
            ws->etok[e2 * S_TOK + i2] = t;
            ws->eval[e2 * S_TOK + i2] = v2;
            ws->e1a[t] = e1; ws->e2a[t] = e2;
            ws->g1a[t] = g1; ws->g2a[t] = g2;
        }
    }
    __syncthreads();
    if (tid < NE) atomicAdd(&ws->gate_sum[tid], gsumL[tid]);
}

// Kernel 2: per-expert capacity filter (exact dense-column rank semantics of
// top_k over topk_masked_gates.T, including zeros for unassigned tokens),
// then per-expert kept-token locations (cumsum order = token index order).
__global__ __launch_bounds__(256) void k_capacity(Ws* __restrict__ ws) {
    __shared__ float vals[S_TOK];
    __shared__ int   toks[S_TOK];
    __shared__ unsigned char kept[S_TOK];

    const int e = blockIdx.x;
    const int n = ws->ecount[e];

    for (int i = threadIdx.x; i < n; i += 256) {
        vals[i] = ws->eval[e * S_TOK + i];
        toks[i] = ws->etok[e * S_TOK + i];
    }
    __syncthreads();

    for (int i = threadIdx.x; i < n; i += 256) {
        float v = vals[i];
        int   t = toks[i];
        // dense rank: zeros (S-n of them) outrank v if v<0; ties -> lower index
        int rank = (v < 0.f) ? (S_TOK - n) : 0;
        int alt  = 0;
        for (int j = 0; j < n; ++j) {
            float vj = vals[j]; int tj = toks[j];
            rank += (vj > v || (vj == v && tj < t)) ? 1 : 0;
            alt  += (tj < t) ? 1 : 0;
        }
        if (v == 0.f) rank += t - alt;   // zeros tie with v==0 at lower index
        kept[i] = (rank < CAP) ? 1 : 0;
    }
    __syncthreads();

    for (int i = threadIdx.x; i < n; i += 256) {
        if (!kept[i]) continue;
        int t = toks[i];
        int loc = 0;
        for (int j = 0; j < n; ++j) loc += (kept[j] && toks[j] < t) ? 1 : 0;
        atomicAdd(&ws->loc_s[t], loc);
        if (ws->e1a[t] == e) ws->keptA[t] = 1;
        else                 ws->keptB[t] = 1;
    }
}

// Kernel 3: scatter nonzeros of combine_weights / dispatch_mask.
__global__ __launch_bounds__(256) void k_scatter(const Ws* __restrict__ ws,
                                                 float* __restrict__ out) {
    int t = blockIdx.x * blockDim.x + threadIdx.x;
    if (t >= S_TOK) return;
    int kA = ws->keptA[t], kB = ws->keptB[t];
    if (!(kA | kB)) return;
    float g1 = ws->g1a[t], g2 = ws->g2a[t];
    float d = (kA ? g1 : 0.f) + (kB ? g2 : 0.f);
    d = fmaxf(d, 1.1920929e-07f);                // finfo(f32).eps clip
    int loc = ws->loc_s[t];
    if (loc >= CAP) return;                      // one_hot out-of-range -> zeros
    float* cw = out + 1;
    float* dm = out + 1 + (size_t)S_TOK * NE * CAP;
    if (kA) {
        size_t idx = (size_t)t * NE * CAP + (size_t)ws->e1a[t] * CAP + loc;
        cw[idx] = g1 / d; dm[idx] = 1.f;
    }
    if (kB) {
        size_t idx = (size_t)t * NE * CAP + (size_t)ws->e2a[t] * CAP + loc;
        cw[idx] = g2 / d; dm[idx] = 1.f;
    }
}

// Kernel 4: l_aux and exp_counts.
__global__ __launch_bounds__(64) void k_final(const Ws* __restrict__ ws,
                                              float* __restrict__ out) {
    int tid = threadIdx.x;
    float part = 0.f;
    if (tid < NE) {
        int c = ws->counts[tid];
        out[1 + 2 * (size_t)S_TOK * NE * CAP + tid] = (float)c;
        float me = ws->gate_sum[tid] / (float)S_TOK;
        float ce = (float)c / (float)S_TOK;
        part = me * ce;
    }
    #pragma unroll
    for (int m = 16; m >= 1; m >>= 1) part += __shfl_xor(part, m);
    if (tid == 0) out[0] = part * ((float)NE * (float)NE / 2.0f / (float)NE); // = sum*16
}

extern "C" void kernel_launch(void* const* d_in, const int* in_sizes, int n_in,
                              void* d_out, int out_size, void* d_ws, size_t ws_size,
                              hipStream_t stream) {
    const float* x  = (const float*)d_in[0];
    const float* wg = (const float*)d_in[1];
    float* out = (float*)d_out;
    Ws* ws = (Ws*)d_ws;

    // zero the accumulator region of the workspace and the whole output
    hipMemsetAsync(d_ws, 0, offsetof(Ws, e1a), stream);
    hipMemsetAsync(d_out, 0, (size_t)out_size * sizeof(float), stream);

    k_gate<<<S_TOK / TOKB, TPB, 0, stream>>>(x, wg, ws);
    k_capacity<<<NE, 256, 0, stream>>>(ws);
    k_scatter<<<S_TOK / 256, 256, 0, stream>>>(ws, out);
    k_final<<<1, 64, 0, stream>>>(ws, out);
}